// Round 1
// baseline (4959.604 us; speedup 1.0000x reference)
//
#include <hip/hip_runtime.h>
#include <cmath>

#define T_DIM 2048
#define H_DIM 2048
#define NH    16
#define NKV   4
#define HD    128
#define NE    8
#define I_DIM 4096
#define QS    2048   // NH*HD
#define KVS   512    // NKV*HD
#define QKV_N 3072   // QS + 2*KVS
#define PADMAX 2560  // T + NE*64 worst-case padded rows
#define MAXRB  40    // PADMAX/64

constexpr int ST_PLAIN = 0, ST_RESID = 1, ST_ACCUM = 2, ST_SCATTER = 3, ST_SILU = 4;

__device__ __forceinline__ float waveReduceSum(float v) {
#pragma unroll
  for (int o = 32; o; o >>= 1) v += __shfl_xor(v, o, 64);
  return v;
}
__device__ __forceinline__ float waveReduceMax(float v) {
#pragma unroll
  for (int o = 32; o; o >>= 1) v = fmaxf(v, __shfl_xor(v, o, 64));
  return v;
}

// ---------------- rmsnorm over H=2048 (one block per token) ----------------
__global__ __launch_bounds__(256) void rmsnorm_kernel(const float* __restrict__ in,
                                                      const float* __restrict__ w,
                                                      float* __restrict__ out) {
  int t = blockIdx.x, tid = threadIdx.x;
  const float* row = in + (size_t)t * H_DIM;
  float4 a = *(const float4*)(row + tid * 4);
  float4 b = *(const float4*)(row + (tid + 256) * 4);
  float ss = a.x * a.x + a.y * a.y + a.z * a.z + a.w * a.w +
             b.x * b.x + b.y * b.y + b.z * b.z + b.w * b.w;
  __shared__ float red[4];
  float sw = waveReduceSum(ss);
  if ((tid & 63) == 0) red[tid >> 6] = sw;
  __syncthreads();
  float tot = red[0] + red[1] + red[2] + red[3];
  float r = rsqrtf(tot / (float)H_DIM + 1e-5f);
  float4 wa = *(const float4*)(w + tid * 4);
  float4 wb = *(const float4*)(w + (tid + 256) * 4);
  float* orow = out + (size_t)t * H_DIM;
  *(float4*)(orow + tid * 4) = make_float4(a.x * r * wa.x, a.y * r * wa.y, a.z * r * wa.z, a.w * r * wa.w);
  *(float4*)(orow + (tid + 256) * 4) = make_float4(b.x * r * wb.x, b.y * r * wb.y, b.z * r * wb.z, b.w * r * wb.w);
}

// -------- rope (theta=5e5) then rmsnorm over full q (2048) / k (512), in place in qkv --------
__global__ __launch_bounds__(256) void rope_norm_kernel(float* __restrict__ qkv,
                                                        const int* __restrict__ pos,
                                                        const float* __restrict__ qw,
                                                        const float* __restrict__ kw) {
  int t = blockIdx.x, tid = threadIdx.x;
  float* row = qkv + (size_t)t * QKV_N;
  float fpos = (float)pos[t];
  const float k2 = 18.931568569324174f / 64.f;  // log2(theta)/64
  float q1[4], q2[4];
  float ss = 0.f;
#pragma unroll
  for (int i = 0; i < 4; i++) {
    int p = tid + 256 * i;
    int hh = p >> 6, d = p & 63;
    float fr = fpos * exp2f(-(float)d * k2);
    float s, c;
    sincosf(fr, &s, &c);
    float x1 = row[hh * 128 + d];
    float x2 = row[hh * 128 + 64 + d];
    q1[i] = x1 * c - x2 * s;
    q2[i] = x2 * c + x1 * s;
    ss += q1[i] * q1[i] + q2[i] * q2[i];
  }
  __shared__ float redA[4], redB[4];
  int lane = tid & 63, wid = tid >> 6;
  float sw = waveReduceSum(ss);
  if (lane == 0) redA[wid] = sw;
  // k part: one pair per thread (4 heads * 64 pairs = 256)
  int hk = tid >> 6, dk = tid & 63;
  float frk = fpos * exp2f(-(float)dk * k2);
  float sk, ck;
  sincosf(frk, &sk, &ck);
  float* krow = row + QS;
  float kx1 = krow[hk * 128 + dk], kx2 = krow[hk * 128 + 64 + dk];
  float k1v = kx1 * ck - kx2 * sk;
  float k2v = kx2 * ck + kx1 * sk;
  float ssk = waveReduceSum(k1v * k1v + k2v * k2v);
  if (lane == 0) redB[wid] = ssk;
  __syncthreads();
  float rq = rsqrtf((redA[0] + redA[1] + redA[2] + redA[3]) / (float)QS + 1e-5f);
  float rk = rsqrtf((redB[0] + redB[1] + redB[2] + redB[3]) / (float)KVS + 1e-5f);
#pragma unroll
  for (int i = 0; i < 4; i++) {
    int p = tid + 256 * i;
    int hh = p >> 6, d = p & 63;
    int i1 = hh * 128 + d, i2 = i1 + 64;
    row[i1] = q1[i] * rq * qw[i1];
    row[i2] = q2[i] * rq * qw[i2];
  }
  int i1 = hk * 128 + dk, i2 = i1 + 64;
  krow[i1] = k1v * rk * kw[i1];
  krow[i2] = k2v * rk * kw[i2];
}

// ---------------- GQA causal flash attention ----------------
// block = (t, kv-group g); 4 waves = q-heads g*4..g*4+3 (uniform loop trips -> safe barriers)
#define AST 132
__global__ __launch_bounds__(256) void attn_kernel(const float* __restrict__ qkv,
                                                   float* __restrict__ outp) {
  __shared__ float KV[64 * AST];
  __shared__ float qsh[4][128];
  __shared__ float psh[4][64];
  int bx = blockIdx.x;
  int g = bx & 3;
  int t = (T_DIM - 1) - (bx >> 2);  // heavy blocks first
  int tid = threadIdx.x, wid = tid >> 6, lane = tid & 63;
  int h = g * 4 + wid;
  const float* qrow = qkv + (size_t)t * QKV_N + h * HD;
  float qa = qrow[2 * lane], qb = qrow[2 * lane + 1];
  qsh[wid][2 * lane] = qa;
  qsh[wid][2 * lane + 1] = qb;
  float o0 = 0.f, o1 = 0.f, m = -1e30f, l = 0.f;
  const float scale = 0.08838834764831845f;  // 1/sqrt(128)
  __syncthreads();
  for (int s0 = 0; s0 <= t; s0 += 64) {
    // stage K tile
#pragma unroll
    for (int it = 0; it < 8; ++it) {
      int li = it * 256 + tid;
      int r = li >> 5, c4 = li & 31;
      int s = s0 + r;
      float4 kv = (s < T_DIM) ? *(const float4*)(qkv + (size_t)s * QKV_N + QS + g * HD + c4 * 4)
                              : make_float4(0, 0, 0, 0);
      *(float4*)&KV[r * AST + c4 * 4] = kv;
    }
    __syncthreads();
    int sKey = s0 + lane;
    bool valid = (sKey <= t);
    float dot = 0.f;
#pragma unroll
    for (int d4 = 0; d4 < 32; ++d4) {
      float4 kk = *(const float4*)&KV[lane * AST + d4 * 4];
      float4 qq = *(const float4*)&qsh[wid][d4 * 4];
      dot = fmaf(kk.x, qq.x, fmaf(kk.y, qq.y, fmaf(kk.z, qq.z, fmaf(kk.w, qq.w, dot))));
    }
    dot = valid ? dot * scale : -1e30f;
    float mt = waveReduceMax(dot);
    float mnew = fmaxf(m, mt);
    float alpha = __expf(m - mnew);
    float p = valid ? __expf(dot - mnew) : 0.f;
    float psum = waveReduceSum(p);
    l = l * alpha + psum;
    o0 *= alpha;
    o1 *= alpha;
    psh[wid][lane] = p;
    m = mnew;
    __syncthreads();  // all waves done reading K
    // stage V tile into the same buffer
#pragma unroll
    for (int it = 0; it < 8; ++it) {
      int li = it * 256 + tid;
      int r = li >> 5, c4 = li & 31;
      int s = s0 + r;
      float4 vv = (s < T_DIM) ? *(const float4*)(qkv + (size_t)s * QKV_N + QS + KVS + g * HD + c4 * 4)
                              : make_float4(0, 0, 0, 0);
      *(float4*)&KV[r * AST + c4 * 4] = vv;
    }
    __syncthreads();
#pragma unroll
    for (int key = 0; key < 64; key += 4) {
      float4 pk = *(const float4*)&psh[wid][key];
      float2 v0 = *(const float2*)&KV[(key + 0) * AST + 2 * lane];
      float2 v1 = *(const float2*)&KV[(key + 1) * AST + 2 * lane];
      float2 v2 = *(const float2*)&KV[(key + 2) * AST + 2 * lane];
      float2 v3 = *(const float2*)&KV[(key + 3) * AST + 2 * lane];
      o0 += pk.x * v0.x + pk.y * v1.x + pk.z * v2.x + pk.w * v3.x;
      o1 += pk.x * v0.y + pk.y * v1.y + pk.z * v2.y + pk.w * v3.y;
    }
    __syncthreads();  // before next K staging overwrites KV
  }
  float inv = 1.f / l;
  *(float2*)&outp[(size_t)t * QS + h * HD + 2 * lane] = make_float2(o0 * inv, o1 * inv);
}

// ---------------- router: logits = y @ router_w (H x 8), top-1 + sigmoid ----------------
__global__ __launch_bounds__(256) void router_kernel(const float* __restrict__ y,
                                                     const float* __restrict__ rw,
                                                     int* __restrict__ eidx,
                                                     float* __restrict__ gate) {
  int t = blockIdx.x, tid = threadIdx.x;
  const float* row = y + (size_t)t * H_DIM;
  float4 xa = *(const float4*)(row + tid * 8);
  float4 xb = *(const float4*)(row + tid * 8 + 4);
  float xv[8] = {xa.x, xa.y, xa.z, xa.w, xb.x, xb.y, xb.z, xb.w};
  float acc[8] = {0, 0, 0, 0, 0, 0, 0, 0};
#pragma unroll
  for (int i = 0; i < 8; i++) {
    const float* r8 = rw + (size_t)(tid * 8 + i) * 8;
    float4 ra = *(const float4*)(r8);
    float4 rb = *(const float4*)(r8 + 4);
    acc[0] = fmaf(xv[i], ra.x, acc[0]);
    acc[1] = fmaf(xv[i], ra.y, acc[1]);
    acc[2] = fmaf(xv[i], ra.z, acc[2]);
    acc[3] = fmaf(xv[i], ra.w, acc[3]);
    acc[4] = fmaf(xv[i], rb.x, acc[4]);
    acc[5] = fmaf(xv[i], rb.y, acc[5]);
    acc[6] = fmaf(xv[i], rb.z, acc[6]);
    acc[7] = fmaf(xv[i], rb.w, acc[7]);
  }
  __shared__ float red[4][8];
  int lane = tid & 63, wid = tid >> 6;
#pragma unroll
  for (int e = 0; e < 8; e++) acc[e] = waveReduceSum(acc[e]);
  if (lane == 0) {
#pragma unroll
    for (int e = 0; e < 8; e++) red[wid][e] = acc[e];
  }
  __syncthreads();
  if (tid == 0) {
    float best = -1e30f;
    int be = 0;
#pragma unroll
    for (int e = 0; e < 8; e++) {
      float v = red[0][e] + red[1][e] + red[2][e] + red[3][e];
      if (v > best) { best = v; be = e; }  // strict > keeps lowest index on tie
    }
    eidx[t] = be;
    gate[t] = 1.f / (1.f + expf(-best));
  }
}

// ---------------- MoE routing bookkeeping ----------------
__global__ void moe_prep(int* counts, int* cursor, int* perm) {
  int tid = threadIdx.x;
  if (tid < 8) { counts[tid] = 0; cursor[tid] = 0; }
  for (int i = tid; i < PADMAX; i += 256) perm[i] = -1;
}
__global__ void hist_kernel(const int* __restrict__ eidx, int* counts) {
  int t = blockIdx.x * 256 + threadIdx.x;
  atomicAdd(&counts[eidx[t]], 1);
}
__global__ void scan_kernel(const int* __restrict__ counts, int* poff, int* rbmap) {
  if (threadIdx.x == 0 && blockIdx.x == 0) {
    int off = 0;
    for (int e = 0; e < 8; e++) {
      poff[e] = off;
      off += ((counts[e] + 63) >> 6) << 6;  // pad each expert to 64 rows
    }
    poff[8] = off;
    int nRB = off >> 6;
    for (int rb = 0; rb < 64; rb++) {
      int ee = -1;
      if (rb < nRB) {
        int r0 = rb * 64;
        for (int e = 0; e < 8; e++)
          if (r0 >= poff[e] && r0 < poff[e + 1]) ee = e;
      }
      rbmap[rb] = ee;
    }
  }
}
__global__ void scatter_kernel(const int* __restrict__ eidx, const int* __restrict__ poff,
                               int* cursor, int* perm) {
  int t = blockIdx.x * 256 + threadIdx.x;
  int e = eidx[t];
  int pos = poff[e] + atomicAdd(&cursor[e], 1);
  perm[pos] = t;
}

// ---------------- generic 64x64x16 fp32 tiled GEMM ----------------
// STORE: 0 plain, 1 resid-add, 2 accumulate(+=), 3 gated scatter(+=g*acc via perm), 4 silu(g)*u
// GROUPED: B base += rbmap[mb]*bStride (expert weights); GATHER_A: A row via perm (-1 -> zeros)
template <int STORE, bool DUAL, bool GROUPED, bool GATHER_A>
__global__ __launch_bounds__(256) void gemm_k(const float* __restrict__ A,
                                              const float* __restrict__ B0,
                                              const float* __restrict__ B1,
                                              float* __restrict__ C,
                                              const float* __restrict__ resid,
                                              int K, int N,
                                              const int* __restrict__ perm,
                                              const int* __restrict__ rbmap,
                                              const float* __restrict__ gate,
                                              size_t bStride) {
  __shared__ float As[16][68];
  __shared__ float Bs0[16][64];
  __shared__ float Bs1[DUAL ? 16 : 1][64];
  int tid = threadIdx.x;
  int mb = blockIdx.y, nb = blockIdx.x;
  const float* b0 = B0;
  const float* b1 = B1;
  if constexpr (GROUPED) {
    int e = rbmap[mb];
    if (e < 0) return;  // uniform early exit, before any barrier
    b0 += (size_t)e * bStride;
    if constexpr (DUAL) b1 += (size_t)e * bStride;
  }
  int ar = tid >> 2, ac4 = tid & 3;
  const float* aPtr = nullptr;
  {
    int grow = mb * 64 + ar;
    if constexpr (GATHER_A) {
      int tk = perm[grow];
      if (tk >= 0) aPtr = A + (size_t)tk * K + ac4 * 4;
    } else {
      aPtr = A + (size_t)grow * K + ac4 * 4;
    }
  }
  int brr = tid >> 4, bc4 = tid & 15;
  const float* bPtr0 = b0 + (size_t)brr * N + nb * 64 + bc4 * 4;
  const float* bPtr1 = DUAL ? (b1 + (size_t)brr * N + nb * 64 + bc4 * 4) : nullptr;
  int tx = tid & 15, ty = tid >> 4;
  float acc0[4][4] = {};
  float acc1[4][4] = {};
  for (int k0 = 0; k0 < K; k0 += 16) {
    float4 av = aPtr ? *(const float4*)(aPtr + k0) : make_float4(0, 0, 0, 0);
    As[ac4 * 4 + 0][ar] = av.x;
    As[ac4 * 4 + 1][ar] = av.y;
    As[ac4 * 4 + 2][ar] = av.z;
    As[ac4 * 4 + 3][ar] = av.w;
    *(float4*)&Bs0[brr][bc4 * 4] = *(const float4*)(bPtr0 + (size_t)k0 * N);
    if constexpr (DUAL) *(float4*)&Bs1[brr][bc4 * 4] = *(const float4*)(bPtr1 + (size_t)k0 * N);
    __syncthreads();
#pragma unroll
    for (int kk = 0; kk < 16; kk++) {
      float4 a4 = *(const float4*)&As[kk][ty * 4];
      float4 b4 = *(const float4*)&Bs0[kk][tx * 4];
      float aa[4] = {a4.x, a4.y, a4.z, a4.w};
      float bb[4] = {b4.x, b4.y, b4.z, b4.w};
#pragma unroll
      for (int i = 0; i < 4; i++) {
#pragma unroll
        for (int j = 0; j < 4; j++) acc0[i][j] = fmaf(aa[i], bb[j], acc0[i][j]);
      }
      if constexpr (DUAL) {
        float4 u4 = *(const float4*)&Bs1[kk][tx * 4];
        float uu[4] = {u4.x, u4.y, u4.z, u4.w};
#pragma unroll
        for (int i = 0; i < 4; i++) {
#pragma unroll
          for (int j = 0; j < 4; j++) acc1[i][j] = fmaf(aa[i], uu[j], acc1[i][j]);
        }
      }
    }
    __syncthreads();
  }
#pragma unroll
  for (int i = 0; i < 4; i++) {
    int row = mb * 64 + ty * 4 + i;
    int col = nb * 64 + tx * 4;
    if constexpr (STORE == ST_SILU) {
      float4 hv;
      float* hp = (float*)&hv;
#pragma unroll
      for (int j = 0; j < 4; j++) {
        float gv = acc0[i][j], uv = acc1[i][j];
        hp[j] = gv / (1.f + __expf(-gv)) * uv;
      }
      *(float4*)&C[(size_t)row * N + col] = hv;
    } else if constexpr (STORE == ST_PLAIN) {
      *(float4*)&C[(size_t)row * N + col] =
          make_float4(acc0[i][0], acc0[i][1], acc0[i][2], acc0[i][3]);
    } else if constexpr (STORE == ST_RESID) {
      float4 rv = *(const float4*)&resid[(size_t)row * N + col];
      *(float4*)&C[(size_t)row * N + col] = make_float4(
          rv.x + acc0[i][0], rv.y + acc0[i][1], rv.z + acc0[i][2], rv.w + acc0[i][3]);
    } else if constexpr (STORE == ST_ACCUM) {
      float4 cv = *(float4*)&C[(size_t)row * N + col];
      cv.x += acc0[i][0]; cv.y += acc0[i][1]; cv.z += acc0[i][2]; cv.w += acc0[i][3];
      *(float4*)&C[(size_t)row * N + col] = cv;
    } else {  // ST_SCATTER
      int tk = perm[row];
      if (tk >= 0) {
        float gv = gate[tk];
        float4 cv = *(float4*)&C[(size_t)tk * N + col];
        cv.x += gv * acc0[i][0]; cv.y += gv * acc0[i][1];
        cv.z += gv * acc0[i][2]; cv.w += gv * acc0[i][3];
        *(float4*)&C[(size_t)tk * N + col] = cv;
      }
    }
  }
}

extern "C" void kernel_launch(void* const* d_in, const int* in_sizes, int n_in,
                              void* d_out, int out_size, void* d_ws, size_t ws_size,
                              hipStream_t stream) {
  const int* positions = (const int*)d_in[0];
  const float* hidden = (const float*)d_in[1];
  const float* ln1 = (const float*)d_in[2];
  const float* ln2 = (const float*)d_in[3];
  const float* w_qkv = (const float*)d_in[4];
  const float* w_o = (const float*)d_in[5];
  const float* qnw = (const float*)d_in[6];
  const float* knw = (const float*)d_in[7];
  const float* rw = (const float*)d_in[8];
  const float* wsg = (const float*)d_in[9];
  const float* wsu = (const float*)d_in[10];
  const float* wsd = (const float*)d_in[11];
  const float* weg = (const float*)d_in[12];
  const float* weu = (const float*)d_in[13];
  const float* wed = (const float*)d_in[14];
  float* out = (float*)d_out;
  float* ws = (float*)d_ws;

  // layout: [0, 10485760) region A:  phase1 x1[0,4M) + qkv[4M,10M); attn_raw aliases x1;
  //         phase2 (MoE) h_buf = full region (2560 x 4096 exactly)
  float* x1 = ws;
  float* qkv = ws + 4194304;
  float* attn_raw = ws;
  float* hbuf = ws;
  float* ybuf = ws + 10485760;  // 4M floats
  int* eidx = (int*)(ws + 14680064);
  float* gatew = (float*)(eidx + T_DIM);
  int* counts = (int*)(gatew + T_DIM);
  int* cursor = counts + 8;
  int* poff = cursor + 8;
  int* rbmap = poff + 16;
  int* perm = rbmap + 64;  // PADMAX ints

  // 1. x1 = rmsnorm(hidden, ln1)
  rmsnorm_kernel<<<T_DIM, 256, 0, stream>>>(hidden, ln1, x1);
  // 2. qkv = x1 @ w_qkv
  gemm_k<ST_PLAIN, false, false, false><<<dim3(QKV_N / 64, T_DIM / 64), 256, 0, stream>>>(
      x1, w_qkv, nullptr, qkv, nullptr, H_DIM, QKV_N, nullptr, nullptr, nullptr, 0);
  // 3. rope + q/k rmsnorm, in place
  rope_norm_kernel<<<T_DIM, 256, 0, stream>>>(qkv, positions, qnw, knw);
  // 4. attention -> attn_raw
  attn_kernel<<<T_DIM * NKV, 256, 0, stream>>>(qkv, attn_raw);
  // 5. out = hidden + attn_raw @ w_o
  gemm_k<ST_RESID, false, false, false><<<dim3(H_DIM / 64, T_DIM / 64), 256, 0, stream>>>(
      attn_raw, w_o, nullptr, out, hidden, QS, H_DIM, nullptr, nullptr, nullptr, 0);
  // 6. y = rmsnorm(out, ln2)
  rmsnorm_kernel<<<T_DIM, 256, 0, stream>>>(out, ln2, ybuf);
  // 7. router top-1
  router_kernel<<<T_DIM, 256, 0, stream>>>(ybuf, rw, eidx, gatew);
  // 8-11. routing bookkeeping
  moe_prep<<<1, 256, 0, stream>>>(counts, cursor, perm);
  hist_kernel<<<T_DIM / 256, 256, 0, stream>>>(eidx, counts);
  scan_kernel<<<1, 64, 0, stream>>>(counts, poff, rbmap);
  scatter_kernel<<<T_DIM / 256, 256, 0, stream>>>(eidx, poff, cursor, perm);
  // 12. expert gate/up (gathered rows, grouped B) -> hbuf
  gemm_k<ST_SILU, true, true, true><<<dim3(I_DIM / 64, MAXRB), 256, 0, stream>>>(
      ybuf, weg, weu, hbuf, nullptr, H_DIM, I_DIM, perm, rbmap, nullptr, (size_t)H_DIM * I_DIM);
  // 13. expert down, gated scatter-add into out
  gemm_k<ST_SCATTER, false, true, false><<<dim3(H_DIM / 64, MAXRB), 256, 0, stream>>>(
      hbuf, wed, nullptr, out, nullptr, I_DIM, H_DIM, perm, rbmap, gatew, (size_t)I_DIM * H_DIM);
  // 14. shared gate/up -> hbuf (rows 0..T)
  gemm_k<ST_SILU, true, false, false><<<dim3(I_DIM / 64, T_DIM / 64), 256, 0, stream>>>(
      ybuf, wsg, wsu, hbuf, nullptr, H_DIM, I_DIM, nullptr, nullptr, nullptr, 0);
  // 15. out += shared_h @ ws_down
  gemm_k<ST_ACCUM, false, false, false><<<dim3(H_DIM / 64, T_DIM / 64), 256, 0, stream>>>(
      hbuf, wsd, nullptr, out, nullptr, I_DIM, H_DIM, nullptr, nullptr, nullptr, 0);

  (void)in_sizes; (void)n_in; (void)out_size; (void)ws_size;
}

// Round 2
// 2788.010 us; speedup vs baseline: 1.7789x; 1.7789x over previous
//
#include <hip/hip_runtime.h>
#include <cmath>

#define T_DIM 2048
#define H_DIM 2048
#define NH    16
#define NKV   4
#define HD    128
#define NE    8
#define I_DIM 4096
#define QS    2048   // NH*HD
#define KVS   512    // NKV*HD
#define QKV_N 3072   // QS + 2*KVS
#define PADMAX 3072  // T + NE*127 rounded up to 128-blocks
#define MAXRB  24    // PADMAX/128

#define BM 128
#define BN 128
#define BK 32
#define LP 40        // LDS row pitch in shorts (80B: 16B-aligned, 2-way-max frag-read conflicts)

constexpr int ST_PLAIN = 0, ST_RESID = 1, ST_ACCUM = 2, ST_SCATTER = 3, ST_SILU = 4;

typedef __attribute__((ext_vector_type(8))) short bf16x8;
typedef __attribute__((ext_vector_type(4))) float f32x4;

__device__ __forceinline__ unsigned short f2bf(float f) {
  unsigned u = __float_as_uint(f);
  u += 0x7fff + ((u >> 16) & 1);  // RNE
  return (unsigned short)(u >> 16);
}
__device__ __forceinline__ float bf2f(unsigned short h) {
  return __uint_as_float(((unsigned)h) << 16);
}

__device__ __forceinline__ float waveReduceSum(float v) {
#pragma unroll
  for (int o = 32; o; o >>= 1) v += __shfl_xor(v, o, 64);
  return v;
}
__device__ __forceinline__ float waveReduceMax(float v) {
#pragma unroll
  for (int o = 32; o; o >>= 1) v = fmaxf(v, __shfl_xor(v, o, 64));
  return v;
}

// ---------------- rmsnorm over H=2048 (one block per token) ----------------
// Always writes bf16 hi; optionally fp32 (router needs exact y) and bf16 lo (split GEMM A).
template <bool WF32, bool WLO>
__global__ __launch_bounds__(256) void rmsnorm_kernel(const float* __restrict__ in,
                                                      const float* __restrict__ w,
                                                      float* __restrict__ outf,
                                                      ushort* __restrict__ ohi,
                                                      ushort* __restrict__ olo) {
  int t = blockIdx.x, tid = threadIdx.x;
  const float* row = in + (size_t)t * H_DIM;
  float4 a = *(const float4*)(row + tid * 4);
  float4 b = *(const float4*)(row + (tid + 256) * 4);
  float ss = a.x * a.x + a.y * a.y + a.z * a.z + a.w * a.w +
             b.x * b.x + b.y * b.y + b.z * b.z + b.w * b.w;
  __shared__ float red[4];
  float sw = waveReduceSum(ss);
  if ((tid & 63) == 0) red[tid >> 6] = sw;
  __syncthreads();
  float tot = red[0] + red[1] + red[2] + red[3];
  float r = rsqrtf(tot / (float)H_DIM + 1e-5f);
  float4 wa = *(const float4*)(w + tid * 4);
  float4 wb = *(const float4*)(w + (tid + 256) * 4);
  float4 ra = make_float4(a.x * r * wa.x, a.y * r * wa.y, a.z * r * wa.z, a.w * r * wa.w);
  float4 rb = make_float4(b.x * r * wb.x, b.y * r * wb.y, b.z * r * wb.z, b.w * r * wb.w);
  size_t o0 = (size_t)t * H_DIM + tid * 4;
  size_t o1 = (size_t)t * H_DIM + (tid + 256) * 4;
  if constexpr (WF32) {
    *(float4*)(outf + o0) = ra;
    *(float4*)(outf + o1) = rb;
  }
  ushort4 ha = make_ushort4(f2bf(ra.x), f2bf(ra.y), f2bf(ra.z), f2bf(ra.w));
  ushort4 hb = make_ushort4(f2bf(rb.x), f2bf(rb.y), f2bf(rb.z), f2bf(rb.w));
  *(ushort4*)(ohi + o0) = ha;
  *(ushort4*)(ohi + o1) = hb;
  if constexpr (WLO) {
    ushort4 la = make_ushort4(f2bf(ra.x - bf2f(ha.x)), f2bf(ra.y - bf2f(ha.y)),
                              f2bf(ra.z - bf2f(ha.z)), f2bf(ra.w - bf2f(ha.w)));
    ushort4 lb = make_ushort4(f2bf(rb.x - bf2f(hb.x)), f2bf(rb.y - bf2f(hb.y)),
                              f2bf(rb.z - bf2f(hb.z)), f2bf(rb.w - bf2f(hb.w)));
    *(ushort4*)(olo + o0) = la;
    *(ushort4*)(olo + o1) = lb;
  }
}

// -------- rope (theta=5e5) then rmsnorm over full q (2048) / k (512), in place in qkv --------
__global__ __launch_bounds__(256) void rope_norm_kernel(float* __restrict__ qkv,
                                                        const int* __restrict__ pos,
                                                        const float* __restrict__ qw,
                                                        const float* __restrict__ kw) {
  int t = blockIdx.x, tid = threadIdx.x;
  float* row = qkv + (size_t)t * QKV_N;
  float fpos = (float)pos[t];
  const float k2 = 18.931568569324174f / 64.f;  // log2(theta)/64
  float q1[4], q2[4];
  float ss = 0.f;
#pragma unroll
  for (int i = 0; i < 4; i++) {
    int p = tid + 256 * i;
    int hh = p >> 6, d = p & 63;
    float fr = fpos * exp2f(-(float)d * k2);
    float s, c;
    sincosf(fr, &s, &c);
    float x1 = row[hh * 128 + d];
    float x2 = row[hh * 128 + 64 + d];
    q1[i] = x1 * c - x2 * s;
    q2[i] = x2 * c + x1 * s;
    ss += q1[i] * q1[i] + q2[i] * q2[i];
  }
  __shared__ float redA[4], redB[4];
  int lane = tid & 63, wid = tid >> 6;
  float sw = waveReduceSum(ss);
  if (lane == 0) redA[wid] = sw;
  int hk = tid >> 6, dk = tid & 63;
  float frk = fpos * exp2f(-(float)dk * k2);
  float sk, ck;
  sincosf(frk, &sk, &ck);
  float* krow = row + QS;
  float kx1 = krow[hk * 128 + dk], kx2 = krow[hk * 128 + 64 + dk];
  float k1v = kx1 * ck - kx2 * sk;
  float k2v = kx2 * ck + kx1 * sk;
  float ssk = waveReduceSum(k1v * k1v + k2v * k2v);
  if (lane == 0) redB[wid] = ssk;
  __syncthreads();
  float rq = rsqrtf((redA[0] + redA[1] + redA[2] + redA[3]) / (float)QS + 1e-5f);
  float rk = rsqrtf((redB[0] + redB[1] + redB[2] + redB[3]) / (float)KVS + 1e-5f);
#pragma unroll
  for (int i = 0; i < 4; i++) {
    int p = tid + 256 * i;
    int hh = p >> 6, d = p & 63;
    int i1 = hh * 128 + d, i2 = i1 + 64;
    row[i1] = q1[i] * rq * qw[i1];
    row[i2] = q2[i] * rq * qw[i2];
  }
  int i1 = hk * 128 + dk, i2 = i1 + 64;
  krow[i1] = k1v * rk * kw[i1];
  krow[i2] = k2v * rk * kw[i2];
}

// ---------------- GQA causal flash attention (fp32, writes bf16 hi+lo) ----------------
#define AST 132
__global__ __launch_bounds__(256) void attn_kernel(const float* __restrict__ qkv,
                                                   ushort* __restrict__ ohi,
                                                   ushort* __restrict__ olo) {
  __shared__ float KV[64 * AST];
  __shared__ float qsh[4][128];
  __shared__ float psh[4][64];
  int bx = blockIdx.x;
  int g = bx & 3;
  int t = (T_DIM - 1) - (bx >> 2);  // heavy blocks first
  int tid = threadIdx.x, wid = tid >> 6, lane = tid & 63;
  int h = g * 4 + wid;
  const float* qrow = qkv + (size_t)t * QKV_N + h * HD;
  float qa = qrow[2 * lane], qb = qrow[2 * lane + 1];
  qsh[wid][2 * lane] = qa;
  qsh[wid][2 * lane + 1] = qb;
  float o0 = 0.f, o1 = 0.f, m = -1e30f, l = 0.f;
  const float scale = 0.08838834764831845f;
  __syncthreads();
  for (int s0 = 0; s0 <= t; s0 += 64) {
#pragma unroll
    for (int it = 0; it < 8; ++it) {
      int li = it * 256 + tid;
      int r = li >> 5, c4 = li & 31;
      int s = s0 + r;
      float4 kv = (s < T_DIM) ? *(const float4*)(qkv + (size_t)s * QKV_N + QS + g * HD + c4 * 4)
                              : make_float4(0, 0, 0, 0);
      *(float4*)&KV[r * AST + c4 * 4] = kv;
    }
    __syncthreads();
    int sKey = s0 + lane;
    bool valid = (sKey <= t);
    float dot = 0.f;
#pragma unroll
    for (int d4 = 0; d4 < 32; ++d4) {
      float4 kk = *(const float4*)&KV[lane * AST + d4 * 4];
      float4 qq = *(const float4*)&qsh[wid][d4 * 4];
      dot = fmaf(kk.x, qq.x, fmaf(kk.y, qq.y, fmaf(kk.z, qq.z, fmaf(kk.w, qq.w, dot))));
    }
    dot = valid ? dot * scale : -1e30f;
    float mt = waveReduceMax(dot);
    float mnew = fmaxf(m, mt);
    float alpha = __expf(m - mnew);
    float p = valid ? __expf(dot - mnew) : 0.f;
    float psum = waveReduceSum(p);
    l = l * alpha + psum;
    o0 *= alpha;
    o1 *= alpha;
    psh[wid][lane] = p;
    m = mnew;
    __syncthreads();
#pragma unroll
    for (int it = 0; it < 8; ++it) {
      int li = it * 256 + tid;
      int r = li >> 5, c4 = li & 31;
      int s = s0 + r;
      float4 vv = (s < T_DIM) ? *(const float4*)(qkv + (size_t)s * QKV_N + QS + KVS + g * HD + c4 * 4)
                              : make_float4(0, 0, 0, 0);
      *(float4*)&KV[r * AST + c4 * 4] = vv;
    }
    __syncthreads();
#pragma unroll
    for (int key = 0; key < 64; key += 4) {
      float4 pk = *(const float4*)&psh[wid][key];
      float2 v0 = *(const float2*)&KV[(key + 0) * AST + 2 * lane];
      float2 v1 = *(const float2*)&KV[(key + 1) * AST + 2 * lane];
      float2 v2 = *(const float2*)&KV[(key + 2) * AST + 2 * lane];
      float2 v3 = *(const float2*)&KV[(key + 3) * AST + 2 * lane];
      o0 += pk.x * v0.x + pk.y * v1.x + pk.z * v2.x + pk.w * v3.x;
      o1 += pk.x * v0.y + pk.y * v1.y + pk.z * v2.y + pk.w * v3.y;
    }
    __syncthreads();
  }
  float inv = 1.f / l;
  float v0 = o0 * inv, v1 = o1 * inv;
  unsigned short h0 = f2bf(v0), h1 = f2bf(v1);
  unsigned short l0 = f2bf(v0 - bf2f(h0)), l1 = f2bf(v1 - bf2f(h1));
  size_t idx = (size_t)t * QS + h * HD + 2 * lane;
  *(ushort2*)&ohi[idx] = make_ushort2(h0, h1);
  *(ushort2*)&olo[idx] = make_ushort2(l0, l1);
}

// ---------------- router: logits = y @ router_w (fp32!), top-1 + sigmoid ----------------
__global__ __launch_bounds__(256) void router_kernel(const float* __restrict__ y,
                                                     const float* __restrict__ rw,
                                                     int* __restrict__ eidx,
                                                     float* __restrict__ gate) {
  int t = blockIdx.x, tid = threadIdx.x;
  const float* row = y + (size_t)t * H_DIM;
  float4 xa = *(const float4*)(row + tid * 8);
  float4 xb = *(const float4*)(row + tid * 8 + 4);
  float xv[8] = {xa.x, xa.y, xa.z, xa.w, xb.x, xb.y, xb.z, xb.w};
  float acc[8] = {0, 0, 0, 0, 0, 0, 0, 0};
#pragma unroll
  for (int i = 0; i < 8; i++) {
    const float* r8 = rw + (size_t)(tid * 8 + i) * 8;
    float4 ra = *(const float4*)(r8);
    float4 rb = *(const float4*)(r8 + 4);
    acc[0] = fmaf(xv[i], ra.x, acc[0]);
    acc[1] = fmaf(xv[i], ra.y, acc[1]);
    acc[2] = fmaf(xv[i], ra.z, acc[2]);
    acc[3] = fmaf(xv[i], ra.w, acc[3]);
    acc[4] = fmaf(xv[i], rb.x, acc[4]);
    acc[5] = fmaf(xv[i], rb.y, acc[5]);
    acc[6] = fmaf(xv[i], rb.z, acc[6]);
    acc[7] = fmaf(xv[i], rb.w, acc[7]);
  }
  __shared__ float red[4][8];
  int lane = tid & 63, wid = tid >> 6;
#pragma unroll
  for (int e = 0; e < 8; e++) acc[e] = waveReduceSum(acc[e]);
  if (lane == 0) {
#pragma unroll
    for (int e = 0; e < 8; e++) red[wid][e] = acc[e];
  }
  __syncthreads();
  if (tid == 0) {
    float best = -1e30f;
    int be = 0;
#pragma unroll
    for (int e = 0; e < 8; e++) {
      float v = red[0][e] + red[1][e] + red[2][e] + red[3][e];
      if (v > best) { best = v; be = e; }
    }
    eidx[t] = be;
    gate[t] = 1.f / (1.f + expf(-best));
  }
}

// ---------------- MoE routing bookkeeping (128-row padding per expert) ----------------
__global__ void moe_prep(int* counts, int* cursor, int* perm) {
  int tid = threadIdx.x;
  if (tid < 8) { counts[tid] = 0; cursor[tid] = 0; }
  for (int i = tid; i < PADMAX; i += 256) perm[i] = -1;
}
__global__ void hist_kernel(const int* __restrict__ eidx, int* counts) {
  int t = blockIdx.x * 256 + threadIdx.x;
  atomicAdd(&counts[eidx[t]], 1);
}
__global__ void scan_kernel(const int* __restrict__ counts, int* poff, int* rbmap) {
  if (threadIdx.x == 0 && blockIdx.x == 0) {
    int off = 0;
    for (int e = 0; e < 8; e++) {
      poff[e] = off;
      off += ((counts[e] + 127) >> 7) << 7;
    }
    poff[8] = off;
    int nRB = off >> 7;
    for (int rb = 0; rb < MAXRB; rb++) {
      int ee = -1;
      if (rb < nRB) {
        int r0 = rb * 128;
        for (int e = 0; e < 8; e++)
          if (r0 >= poff[e] && r0 < poff[e + 1]) ee = e;
      }
      rbmap[rb] = ee;
    }
  }
}
__global__ void scatter_kernel(const int* __restrict__ eidx, const int* __restrict__ poff,
                               int* cursor, int* perm) {
  int t = blockIdx.x * 256 + threadIdx.x;
  int e = eidx[t];
  int pos = poff[e] + atomicAdd(&cursor[e], 1);
  perm[pos] = t;
}

// ---------------- bf16 MFMA GEMM: 128x128x32 tile, 256 thr (4 waves 2x2) ----------------
// A: bf16 (hi[,lo]) M-major; B: fp32 [K][N] global, converted to bf16 in staging.
// SPLIT: 3-term bf16x2 product (fp32-class accuracy). DUAL: second B (gate+up).
// GROUPED: B += rbmap[mb]*bStride; GATHER_A: A row via perm (-1 -> zeros).
template <int STORE, bool DUAL, bool GROUPED, bool GATHER_A, bool SPLIT>
__global__ __launch_bounds__(256) void gemm_mfma(
    const ushort* __restrict__ Ahi, const ushort* __restrict__ Alo,
    const float* __restrict__ B0, const float* __restrict__ B1g,
    float* __restrict__ C, ushort* __restrict__ C16,
    const float* __restrict__ resid, int K, int N,
    const int* __restrict__ perm, const int* __restrict__ rbmap,
    const float* __restrict__ gate, size_t bStride) {
  __shared__ short As[(SPLIT ? 2 : 1) * BM * LP];
  __shared__ short Bs[((SPLIT || DUAL) ? 2 : 1) * BM * LP];
  short* As2 = As + BM * LP;  // A lo
  short* Bs2 = Bs + BM * LP;  // B lo, or B1 (dual)
  int tid = threadIdx.x;
  int mb = blockIdx.y, nb = blockIdx.x;
  const float* b0 = B0;
  const float* b1 = B1g;
  if constexpr (GROUPED) {
    int e = rbmap[mb];
    if (e < 0) return;  // uniform exit before any barrier
    b0 += (size_t)e * bStride;
    if constexpr (DUAL) b1 += (size_t)e * bStride;
  }
  // A staging: thread -> (row am, k-half), 16 contiguous bf16 each
  int am = tid >> 1, ak = (tid & 1) * 16;
  const ushort* aP = nullptr;
  const ushort* aPlo = nullptr;
  {
    int grow = mb * BM + am;
    if constexpr (GATHER_A) {
      int tk = perm[grow];
      if (tk >= 0) aP = Ahi + (size_t)tk * K + ak;
    } else {
      aP = Ahi + (size_t)grow * K + ak;
      if constexpr (SPLIT) aPlo = Alo + (size_t)grow * K + ak;
    }
  }
  // B staging: thread -> (4 k-rows at kq*4, 4 n-cols at n4*4); transpose to [n][k] in LDS
  int n4 = tid & 31, kq = tid >> 5;
  const float* bP0 = b0 + (size_t)(kq * 4) * N + nb * BN + n4 * 4;
  const float* bP1 = DUAL ? (b1 + (size_t)(kq * 4) * N + nb * BN + n4 * 4) : nullptr;
  int lane = tid & 63, wv = tid >> 6;
  int wM = (wv >> 1) * 64, wN = (wv & 1) * 64;
  int l15 = lane & 15, quad = lane >> 4;
  f32x4 acc0[4][4];
  f32x4 acc1[4][4];
#pragma unroll
  for (int i = 0; i < 4; i++)
#pragma unroll
    for (int j = 0; j < 4; j++) {
      acc0[i][j] = (f32x4){0.f, 0.f, 0.f, 0.f};
      if constexpr (DUAL) acc1[i][j] = (f32x4){0.f, 0.f, 0.f, 0.f};
    }
  for (int k0 = 0; k0 < K; k0 += BK) {
    // ---- stage A ----
    {
      uint4 v0, v1;
      if (aP) {
        v0 = *(const uint4*)(const void*)(aP + k0);
        v1 = *(const uint4*)(const void*)(aP + k0 + 8);
      } else {
        v0 = make_uint4(0, 0, 0, 0);
        v1 = v0;
      }
      *(uint4*)(void*)&As[am * LP + ak] = v0;
      *(uint4*)(void*)&As[am * LP + ak + 8] = v1;
      if constexpr (SPLIT) {
        uint4 w0 = *(const uint4*)(const void*)(aPlo + k0);
        uint4 w1 = *(const uint4*)(const void*)(aPlo + k0 + 8);
        *(uint4*)(void*)&As2[am * LP + ak] = w0;
        *(uint4*)(void*)&As2[am * LP + ak + 8] = w1;
      }
    }
    // ---- stage B (transpose + fp32->bf16) ----
    {
      float bv[4][4];
#pragma unroll
      for (int i = 0; i < 4; i++) {
        float4 t = *(const float4*)(bP0 + (size_t)(k0 + i) * N);
        bv[i][0] = t.x; bv[i][1] = t.y; bv[i][2] = t.z; bv[i][3] = t.w;
      }
#pragma unroll
      for (int j = 0; j < 4; j++) {
        ushort4 p = make_ushort4(f2bf(bv[0][j]), f2bf(bv[1][j]), f2bf(bv[2][j]), f2bf(bv[3][j]));
        *(ushort4*)(void*)&Bs[(n4 * 4 + j) * LP + kq * 4] = p;
        if constexpr (SPLIT) {
          ushort4 q = make_ushort4(f2bf(bv[0][j] - bf2f(p.x)), f2bf(bv[1][j] - bf2f(p.y)),
                                   f2bf(bv[2][j] - bf2f(p.z)), f2bf(bv[3][j] - bf2f(p.w)));
          *(ushort4*)(void*)&Bs2[(n4 * 4 + j) * LP + kq * 4] = q;
        }
      }
      if constexpr (DUAL) {
        float cv[4][4];
#pragma unroll
        for (int i = 0; i < 4; i++) {
          float4 t = *(const float4*)(bP1 + (size_t)(k0 + i) * N);
          cv[i][0] = t.x; cv[i][1] = t.y; cv[i][2] = t.z; cv[i][3] = t.w;
        }
#pragma unroll
        for (int j = 0; j < 4; j++) {
          ushort4 p = make_ushort4(f2bf(cv[0][j]), f2bf(cv[1][j]), f2bf(cv[2][j]), f2bf(cv[3][j]));
          *(ushort4*)(void*)&Bs2[(n4 * 4 + j) * LP + kq * 4] = p;
        }
      }
    }
    __syncthreads();
    // ---- fragments + MFMA ----
    {
      const short* aB = &As[(wM + l15) * LP + quad * 8];
      const short* bB = &Bs[(wN + l15) * LP + quad * 8];
      bf16x8 af[4], bf_[4];
#pragma unroll
      for (int i = 0; i < 4; i++) af[i] = *(const bf16x8*)(const void*)(aB + i * 16 * LP);
#pragma unroll
      for (int i = 0; i < 4; i++) bf_[i] = *(const bf16x8*)(const void*)(bB + i * 16 * LP);
      if constexpr (SPLIT) {
        const short* aB2 = &As2[(wM + l15) * LP + quad * 8];
        const short* bB2 = &Bs2[(wN + l15) * LP + quad * 8];
        bf16x8 afl[4], bfl[4];
#pragma unroll
        for (int i = 0; i < 4; i++) afl[i] = *(const bf16x8*)(const void*)(aB2 + i * 16 * LP);
#pragma unroll
        for (int i = 0; i < 4; i++) bfl[i] = *(const bf16x8*)(const void*)(bB2 + i * 16 * LP);
#pragma unroll
        for (int rt = 0; rt < 4; rt++)
#pragma unroll
          for (int ct = 0; ct < 4; ct++) {
            acc0[rt][ct] = __builtin_amdgcn_mfma_f32_16x16x32_bf16(af[rt], bf_[ct], acc0[rt][ct], 0, 0, 0);
            acc0[rt][ct] = __builtin_amdgcn_mfma_f32_16x16x32_bf16(afl[rt], bf_[ct], acc0[rt][ct], 0, 0, 0);
            acc0[rt][ct] = __builtin_amdgcn_mfma_f32_16x16x32_bf16(af[rt], bfl[ct], acc0[rt][ct], 0, 0, 0);
          }
      } else if constexpr (DUAL) {
        const short* bB2 = &Bs2[(wN + l15) * LP + quad * 8];
        bf16x8 bu[4];
#pragma unroll
        for (int i = 0; i < 4; i++) bu[i] = *(const bf16x8*)(const void*)(bB2 + i * 16 * LP);
#pragma unroll
        for (int rt = 0; rt < 4; rt++)
#pragma unroll
          for (int ct = 0; ct < 4; ct++) {
            acc0[rt][ct] = __builtin_amdgcn_mfma_f32_16x16x32_bf16(af[rt], bf_[ct], acc0[rt][ct], 0, 0, 0);
            acc1[rt][ct] = __builtin_amdgcn_mfma_f32_16x16x32_bf16(af[rt], bu[ct], acc1[rt][ct], 0, 0, 0);
          }
      } else {
#pragma unroll
        for (int rt = 0; rt < 4; rt++)
#pragma unroll
          for (int ct = 0; ct < 4; ct++)
            acc0[rt][ct] = __builtin_amdgcn_mfma_f32_16x16x32_bf16(af[rt], bf_[ct], acc0[rt][ct], 0, 0, 0);
      }
    }
    __syncthreads();
  }
  // ---- epilogue: C/D layout col=lane&15, row=quad*4+reg ----
#pragma unroll
  for (int rt = 0; rt < 4; rt++) {
#pragma unroll
    for (int r = 0; r < 4; r++) {
      int row = mb * BM + wM + rt * 16 + quad * 4 + r;
      if constexpr (STORE == ST_SCATTER) {
        int tk = perm[row];
        if (tk < 0) continue;
        float g = gate[tk];
        size_t base = (size_t)tk * N;
#pragma unroll
        for (int ct = 0; ct < 4; ct++) {
          int col = nb * BN + wN + ct * 16 + l15;
          C[base + col] += g * acc0[rt][ct][r];
        }
      } else {
        size_t base = (size_t)row * N;
#pragma unroll
        for (int ct = 0; ct < 4; ct++) {
          int col = nb * BN + wN + ct * 16 + l15;
          float v = acc0[rt][ct][r];
          if constexpr (STORE == ST_PLAIN) {
            C[base + col] = v;
          } else if constexpr (STORE == ST_RESID) {
            C[base + col] = resid[base + col] + v;
          } else if constexpr (STORE == ST_ACCUM) {
            C[base + col] += v;
          } else if constexpr (STORE == ST_SILU) {
            float u = acc1[rt][ct][r];
            float hv = v / (1.f + __expf(-v)) * u;
            C16[base + col] = f2bf(hv);
          }
        }
      }
    }
  }
}

extern "C" void kernel_launch(void* const* d_in, const int* in_sizes, int n_in,
                              void* d_out, int out_size, void* d_ws, size_t ws_size,
                              hipStream_t stream) {
  const int* positions = (const int*)d_in[0];
  const float* hidden = (const float*)d_in[1];
  const float* ln1 = (const float*)d_in[2];
  const float* ln2 = (const float*)d_in[3];
  const float* w_qkv = (const float*)d_in[4];
  const float* w_o = (const float*)d_in[5];
  const float* qnw = (const float*)d_in[6];
  const float* knw = (const float*)d_in[7];
  const float* rw = (const float*)d_in[8];
  const float* wsg = (const float*)d_in[9];
  const float* wsu = (const float*)d_in[10];
  const float* wsd = (const float*)d_in[11];
  const float* weg = (const float*)d_in[12];
  const float* weu = (const float*)d_in[13];
  const float* wed = (const float*)d_in[14];
  float* out = (float*)d_out;
  float* ws = (float*)d_ws;

  // workspace layout (floats); total ~16.8M floats = 67.2 MB
  // [0, 6.29M): qkv f32 (phase1) -> hbuf bf16 3072x4096 (phase2, exact alias)
  float* qkv = ws;
  ushort* hbuf = (ushort*)ws;
  // [6.29M, 10.49M): x1 hi/lo bf16 (phase1) -> attn hi/lo bf16 (after qkv GEMM)
  ushort* x1h = (ushort*)(ws + 6291456);
  ushort* x1l = (ushort*)(ws + 6291456 + 2097152);
  ushort* ath = x1h;
  ushort* atl = x1l;
  // [10.49M, 14.68M): ybuf f32 (router needs exact)
  float* ybuf = ws + 10485760;
  // [14.68M, 16.78M): y bf16
  ushort* yb16 = (ushort*)(ws + 14680064);
  // misc
  int* eidx = (int*)(ws + 16777216);
  float* gatew = (float*)(eidx + T_DIM);
  int* counts = (int*)(gatew + T_DIM);
  int* cursor = counts + 8;
  int* poff = cursor + 8;
  int* rbmap = poff + 16;
  int* perm = rbmap + 32;  // PADMAX ints

  // 1. x1 = rmsnorm(hidden, ln1) -> bf16 hi+lo
  rmsnorm_kernel<false, true><<<T_DIM, 256, 0, stream>>>(hidden, ln1, nullptr, x1h, x1l);
  // 2. qkv = x1 @ w_qkv  (split bf16x2, fp32-class)
  gemm_mfma<ST_PLAIN, false, false, false, true><<<dim3(QKV_N / BN, T_DIM / BM), 256, 0, stream>>>(
      x1h, x1l, w_qkv, nullptr, qkv, nullptr, nullptr, H_DIM, QKV_N, nullptr, nullptr, nullptr, 0);
  // 3. rope + q/k rmsnorm, in place (fp32)
  rope_norm_kernel<<<T_DIM, 256, 0, stream>>>(qkv, positions, qnw, knw);
  // 4. attention -> bf16 hi+lo
  attn_kernel<<<T_DIM * NKV, 256, 0, stream>>>(qkv, ath, atl);
  // 5. out = hidden + attn @ w_o  (split)
  gemm_mfma<ST_RESID, false, false, false, true><<<dim3(H_DIM / BN, T_DIM / BM), 256, 0, stream>>>(
      ath, atl, w_o, nullptr, out, nullptr, hidden, QS, H_DIM, nullptr, nullptr, nullptr, 0);
  // 6. y = rmsnorm(out, ln2) -> fp32 (router) + bf16 (GEMMs)
  rmsnorm_kernel<true, false><<<T_DIM, 256, 0, stream>>>(out, ln2, ybuf, yb16, nullptr);
  // 7. router top-1 (fp32 logits: selection must match reference)
  router_kernel<<<T_DIM, 256, 0, stream>>>(ybuf, rw, eidx, gatew);
  // 8-11. routing bookkeeping (128-row padding)
  moe_prep<<<1, 256, 0, stream>>>(counts, cursor, perm);
  hist_kernel<<<T_DIM / 256, 256, 0, stream>>>(eidx, counts);
  scan_kernel<<<1, 64, 0, stream>>>(counts, poff, rbmap);
  scatter_kernel<<<T_DIM / 256, 256, 0, stream>>>(eidx, poff, cursor, perm);
  // 12. expert gate/up (gather rows, grouped B) -> hbuf bf16
  gemm_mfma<ST_SILU, true, true, true, false><<<dim3(I_DIM / BN, MAXRB), 256, 0, stream>>>(
      yb16, nullptr, weg, weu, nullptr, hbuf, nullptr, H_DIM, I_DIM, perm, rbmap, nullptr,
      (size_t)H_DIM * I_DIM);
  // 13. expert down, gated scatter-add into out
  gemm_mfma<ST_SCATTER, false, true, false, false><<<dim3(H_DIM / BN, MAXRB), 256, 0, stream>>>(
      hbuf, nullptr, wed, nullptr, out, nullptr, nullptr, I_DIM, H_DIM, perm, rbmap, gatew,
      (size_t)I_DIM * H_DIM);
  // 14. shared gate/up -> hbuf (rows 0..T, overwrites expert h after it's consumed)
  gemm_mfma<ST_SILU, true, false, false, false><<<dim3(I_DIM / BN, T_DIM / BM), 256, 0, stream>>>(
      yb16, nullptr, wsg, wsu, nullptr, hbuf, nullptr, H_DIM, I_DIM, nullptr, nullptr, nullptr, 0);
  // 15. out += shared_h @ ws_down
  gemm_mfma<ST_ACCUM, false, false, false, false><<<dim3(H_DIM / BN, T_DIM / BM), 256, 0, stream>>>(
      hbuf, nullptr, wsd, nullptr, out, nullptr, nullptr, I_DIM, H_DIM, nullptr, nullptr, nullptr, 0);

  (void)in_sizes; (void)n_in; (void)out_size; (void)ws_size;
}